// Round 5
// baseline (126.158 us; speedup 1.0000x reference)
//
#include <hip/hip_runtime.h>
#include <math.h>

// src (8,3,512,512) f32 | grid1 (8,32,8,16,16) f32 | grid2 (8,27,8,16,16) f32
// out (8,3,512,512) f32
#define BATCH 8
#define IMH 512
#define IMW 512
#define HWSZ (IMH * IMW)
#define CH 32                  // channels per cell in transposed layout (grid2 padded)
#define CPADH 40               // LDS cell stride in halves (80 B: 16B-aligned, 20-bank stride)
#define L_CELLS (16 * 8)       // full row: 16 x-cells * 8 z
#define LSLOTH (L_CELLS * CPADH)   // 5120 halves = 10240 B per slab

typedef _Float16 h1;
typedef _Float16 h2 __attribute__((ext_vector_type(2)));  // -> v_pk_* ops

union V16 {                    // one 16-byte chunk = 8 halves = 4 h2
    uint4 u;
    h2 h[4];
};

__device__ __forceinline__ float fast_tanh(float x) {
    float e = __expf(2.0f * x);
    return fmaf(-2.0f, __builtin_amdgcn_rcpf(e + 1.0f), 1.0f);
}

// ---- transpose+convert: grid1 -> t1 half [b][y][x][z][32], grid2 -> t2 half (ch 27..31 = 0)
__global__ __launch_bounds__(256) void transpose_both(const float* __restrict__ g1,
                                                      const float* __restrict__ g2,
                                                      h1* __restrict__ t1,
                                                      h1* __restrict__ t2) {
    int idx = blockIdx.x * 256 + threadIdx.x;  // 1,048,576 total
    if (idx < 524288) {                        // grid1 [b][c][z][y][x] linear read
        int x = idx & 15, y = (idx >> 4) & 15, z = (idx >> 8) & 7;
        int c = (idx >> 11) & 31, b = idx >> 16;
        t1[((((b * 16 + y) * 16 + x) * 8 + z) << 5) + c] = (h1)g1[idx];
    } else if (idx < 966656) {                 // grid2 (8*27*2048 = 442368)
        int j = idx - 524288;
        int x = j & 15, y = (j >> 4) & 15, z = (j >> 8) & 7;
        int r = j >> 11;
        int c = r % 27, b = r / 27;
        t2[((((b * 16 + y) * 16 + x) * 8 + z) << 5) + c] = (h1)g2[j];
    } else {                                   // zero 5 pad channels (16384 cells * 5)
        int k = idx - 966656;
        int cell = k / 5, p = k - cell * 5;
        t2[(cell << 5) + 27 + p] = (h1)0.0f;
    }
}

// ---- fused pipeline; one block = one full row (512 pixels), 2 pixels per thread
template <bool TR>
__global__ __launch_bounds__(256, 4) void fused5(
    const float* __restrict__ src,
    const void* __restrict__ g1p,   // TR ? half[b][y][x][z][32] : raw f32 grid1
    const void* __restrict__ g2p,
    const float* __restrict__ w1, const float* __restrict__ b1,
    const float* __restrict__ w2, const float* __restrict__ b2,
    const float* __restrict__ w3, const float* __restrict__ b3,
    const float* __restrict__ w4, const float* __restrict__ b4,
    float* __restrict__ out) {
    __shared__ __align__(16) h1 L1h[LSLOTH];  // y-lerped grid1 slab [x16][z8][40h]
    __shared__ __align__(16) h1 L2h[LSLOTH];  // y-lerped grid2 slab

    int tid = threadIdx.x;
    int h = blockIdx.x & 511;
    int b = blockIdx.x >> 9;

    float fy = (float)h * (15.0f / 512.0f);
    int y0 = (int)fy;
    float wy = fy - (float)y0;

    // ---- hoisted src loads for both pixels (overlap with staging) ----
    const float* sbase = src + (size_t)b * 3 * HWSZ + (size_t)h * IMW;
    float sA0 = sbase[tid],           sA1 = sbase[HWSZ + tid],       sA2 = sbase[2 * HWSZ + tid];
    float sB0 = sbase[tid + 256],     sB1 = sbase[HWSZ + tid + 256], sB2 = sbase[2 * HWSZ + tid + 256];

    // ---------------- stage y-interpolated fp16 slabs into LDS ----------------
    if (TR) {
        h2 wyh = (h2)(h1)wy;
        // full row: 128 cells * 4 chunks = 512 contiguous chunks per grid per y-row
        const uint4* p1 = (const uint4*)g1p + ((size_t)b * 16 + y0) * 512;
        const uint4* p2 = (const uint4*)g2p + ((size_t)b * 16 + y0) * 512;
#pragma unroll
        for (int t = tid; t < 512; t += 256) {
            int g = t & 3, cell = t >> 2;
            V16 v0, v1, r0;
            v0.u = p1[t];
            v1.u = p1[t + 512];
#pragma unroll
            for (int k = 0; k < 4; ++k) r0.h[k] = v0.h[k] + (v1.h[k] - v0.h[k]) * wyh;
            *(uint4*)&L1h[cell * CPADH + 8 * g] = r0.u;
            V16 u0, u1, r1;
            u0.u = p2[t];
            u1.u = p2[t + 512];
#pragma unroll
            for (int k = 0; k < 4; ++k) r1.h[k] = u0.h[k] + (u1.h[k] - u0.h[k]) * wyh;
            *(uint4*)&L2h[cell * CPADH + 8 * g] = r1.u;
        }
    } else {  // fallback: scalar stage from raw fp32 grids (slow, correct)
        const float* g1f = (const float*)g1p;
        const float* g2f = (const float*)g2p;
        for (int t = tid; t < L_CELLS * CH; t += 256) {
            int c = t & 31, cell = t >> 5;
            int z = cell & 7, xj = cell >> 3;
            size_t o0 = ((((size_t)b * 32 + c) * 8 + z) * 16 + y0) * 16 + xj;
            float v0 = g1f[o0], v1 = g1f[o0 + 16];
            L1h[cell * CPADH + c] = (h1)fmaf(wy, v1 - v0, v0);
        }
        for (int t = tid; t < L_CELLS * CH; t += 256) {
            int c = t & 31, cell = t >> 5;
            int z = cell & 7, xj = cell >> 3;
            float v = 0.0f;
            if (c < 27) {
                size_t o0 = ((((size_t)b * 27 + c) * 8 + z) * 16 + y0) * 16 + xj;
                v = fmaf(wy, g2f[o0 + 16] - g2f[o0], g2f[o0]);
            }
            L2h[cell * CPADH + c] = (h1)v;
        }
    }
    __syncthreads();

    // ---------------- per-pixel pipeline: 2 pixels per thread ----------------
    float* obase = out + (size_t)b * 3 * HWSZ + (size_t)h * IMW;
#pragma unroll 2
    for (int p = 0; p < 2; ++p) {
        int w = tid + (p << 8);
        float s0 = p ? sB0 : sA0;
        float s1 = p ? sB1 : sA1;
        float s2 = p ? sB2 : sA2;

        // guide MLP #1: 3 -> 16 -> 1 (fp32)
        float acc = b2[0];
#pragma unroll
        for (int j = 0; j < 16; ++j) {
            float t = fmaf(w1[j * 3 + 0], s0,
                      fmaf(w1[j * 3 + 1], s1,
                      fmaf(w1[j * 3 + 2], s2, b1[j])));
            acc = fmaf(w2[j], fmaxf(t, 0.0f), acc);
        }
        float fz = fmaf(fast_tanh(acc), 3.5f, 3.5f);
        fz = fminf(fmaxf(fz, 0.0f), 7.0f);
        int z0 = min((int)fz, 6);
        float wz = fz - (float)z0;

        float fx = (float)w * (15.0f / 512.0f);
        int x0 = (int)fx;
        float wx = fx - (float)x0;
        int a00 = (x0 * 8 + z0) * CPADH;

        float w11v = wx * wz;
        float w10v = wx - w11v;
        float w01v = wz - w11v;
        float w00v = 1.0f - wx - wz + w11v;
        h2 W00 = (h2)(h1)w00v, W01 = (h2)(h1)w01v, W10 = (h2)(h1)w10v, W11 = (h2)(h1)w11v;

        // slice 1: bilinear (x,z) over 32 ch, packed fp16
        const uint4* p00 = (const uint4*)&L1h[a00];
        const uint4* p01 = (const uint4*)&L1h[a00 + CPADH];
        const uint4* p10 = (const uint4*)&L1h[a00 + 8 * CPADH];
        const uint4* p11 = (const uint4*)&L1h[a00 + 9 * CPADH];
        float c1f[32];
#pragma unroll
        for (int j = 0; j < 4; ++j) {
            V16 A, B, C, D;
            A.u = p00[j];
            B.u = p01[j];
            C.u = p10[j];
            D.u = p11[j];
#pragma unroll
            for (int k = 0; k < 4; ++k) {
                h2 r = A.h[k] * W00 + B.h[k] * W01 + C.h[k] * W10 + D.h[k] * W11;
                c1f[j * 8 + 2 * k]     = (float)r[0];
                c1f[j * 8 + 2 * k + 1] = (float)r[1];
            }
        }

        // affine #1: hidden = relu(coeff1 * src) (fp32)
        float hid[8];
#pragma unroll
        for (int o = 0; o < 8; ++o) {
            float t = fmaf(c1f[o], s0,
                      fmaf(c1f[8 + o], s1,
                      fmaf(c1f[16 + o], s2, c1f[24 + o])));
            hid[o] = fmaxf(t, 0.0f);
        }

        // guide MLP #2: 8 -> 16 -> 1 (fp32)
        float acc2 = b4[0];
#pragma unroll
        for (int j = 0; j < 16; ++j) {
            float t = b3[j];
#pragma unroll
            for (int i = 0; i < 8; ++i) t = fmaf(w3[j * 8 + i], hid[i], t);
            acc2 = fmaf(w4[j], fmaxf(t, 0.0f), acc2);
        }
        float fz2 = fmaf(fast_tanh(acc2), 3.5f, 3.5f);
        fz2 = fminf(fmaxf(fz2, 0.0f), 7.0f);
        int z0b = min((int)fz2, 6);
        float wz2 = fz2 - (float)z0b;

        int a00b = (x0 * 8 + z0b) * CPADH;
        float u11 = wx * wz2;
        float u10 = wx - u11;
        float u01 = wz2 - u11;
        float u00 = 1.0f - wx - wz2 + u11;
        h2 U00 = (h2)(h1)u00, U01 = (h2)(h1)u01, U10 = (h2)(h1)u10, U11 = (h2)(h1)u11;

        // slice 2: bilinear (x,z) over 27 real ch (+5 zero pad), packed fp16
        const uint4* q00 = (const uint4*)&L2h[a00b];
        const uint4* q01 = (const uint4*)&L2h[a00b + CPADH];
        const uint4* q10 = (const uint4*)&L2h[a00b + 8 * CPADH];
        const uint4* q11 = (const uint4*)&L2h[a00b + 9 * CPADH];
        float c2f[27];
#pragma unroll
        for (int j = 0; j < 4; ++j) {
            V16 A, B, C, D;
            A.u = q00[j];
            B.u = q01[j];
            C.u = q10[j];
            D.u = q11[j];
#pragma unroll
            for (int k = 0; k < 4; ++k) {
                h2 r = A.h[k] * U00 + B.h[k] * U01 + C.h[k] * U10 + D.h[k] * U11;
                int c = j * 8 + 2 * k;
                if (c < 27)     c2f[c]     = (float)r[0];
                if (c + 1 < 27) c2f[c + 1] = (float)r[1];
            }
        }

        // affine #2 (fp32)
#pragma unroll
        for (int o = 0; o < 3; ++o) {
            float t = c2f[24 + o];
#pragma unroll
            for (int i = 0; i < 8; ++i) t = fmaf(c2f[i * 3 + o], hid[i], t);
            obase[(size_t)o * HWSZ + w] = t;
        }
    }
}

extern "C" void kernel_launch(void* const* d_in, const int* in_sizes, int n_in,
                              void* d_out, int out_size, void* d_ws, size_t ws_size,
                              hipStream_t stream) {
    const float* src   = (const float*)d_in[0];
    const float* grid1 = (const float*)d_in[1];
    const float* grid2 = (const float*)d_in[2];
    const float* w1 = (const float*)d_in[3];
    const float* b1 = (const float*)d_in[4];
    const float* w2 = (const float*)d_in[5];
    const float* b2 = (const float*)d_in[6];
    const float* w3 = (const float*)d_in[7];
    const float* b3 = (const float*)d_in[8];
    const float* w4 = (const float*)d_in[9];
    const float* b4 = (const float*)d_in[10];
    float* out = (float*)d_out;

    const size_t t_elems = (size_t)BATCH * 2048 * CH;     // 524288 halves each
    const size_t ws_needed = 2 * t_elems * sizeof(h1);    // 2 MB

    const int nblk = BATCH * IMH;                         // 4096 (one row each)

    if (ws_size >= ws_needed) {
        h1* t1 = (h1*)d_ws;
        h1* t2 = t1 + t_elems;
        transpose_both<<<4096, 256, 0, stream>>>(grid1, grid2, t1, t2);
        fused5<true><<<nblk, 256, 0, stream>>>(
            src, t1, t2, w1, b1, w2, b2, w3, b3, w4, b4, out);
    } else {
        fused5<false><<<nblk, 256, 0, stream>>>(
            src, grid1, grid2, w1, b1, w2, b2, w3, b3, w4, b4, out);
    }
}

// Round 6
// 119.879 us; speedup vs baseline: 1.0524x; 1.0524x over previous
//
#include <hip/hip_runtime.h>
#include <math.h>

// src (8,3,512,512) f32 | grid1 (8,32,8,16,16) f32 | grid2 (8,27,8,16,16) f32
// out (8,3,512,512) f32
#define BATCH 8
#define IMH 512
#define IMW 512
#define HWSZ (IMH * IMW)
#define CH 32                  // channels per cell in transposed layout (grid2 padded)
#define CPADH 40               // LDS cell stride in halves (80 B: 16B-aligned, 20-bank stride)
#define L_CELLS (16 * 8)       // full row: 16 x-cells * 8 z
#define LSLOTH (L_CELLS * CPADH)   // 5120 halves = 10240 B per slab

typedef _Float16 h1;
typedef _Float16 h2 __attribute__((ext_vector_type(2)));  // -> v_pk_* ops

union V16 {                    // one 16-byte chunk = 8 halves = 4 h2
    uint4 u;
    h2 h[4];
};

__device__ __forceinline__ float fast_tanh(float x) {
    float e = __expf(2.0f * x);
    return fmaf(-2.0f, __builtin_amdgcn_rcpf(e + 1.0f), 1.0f);
}
__device__ __forceinline__ unsigned packh(float a, float b) {
    h2 v;
    v[0] = (h1)a;
    v[1] = (h1)b;
    return __builtin_bit_cast(unsigned, v);
}
__device__ __forceinline__ h2 ash2(unsigned u) { return __builtin_bit_cast(h2, u); }
__device__ __forceinline__ h2 pkmax0(h2 v) { return __builtin_elementwise_max(v, (h2)(h1)0.0f); }

// packed-weight layout (uint32 slots) appended to ws after the two slabs:
//  [0..23]  w1pk[i*8+n] = {w1[2n*3+i], w1[(2n+1)*3+i]}
//  [24..31] b1pk[n]     = {b1[2n], b1[2n+1]}
//  [32..39] w2pk[n]     = {w2[2n], w2[2n+1]}
//  [40..103]w3pk[n*8+i] = {w3[2n*8+i], w3[(2n+1)*8+i]}
//  [104..111]w4pk[n]    = {w4[2n], w4[2n+1]}
//  [112..119]b3pk[n]    = {b3[2n], b3[2n+1]}

// ---- transpose+convert + weight packing
__global__ __launch_bounds__(256) void transpose_both(const float* __restrict__ g1,
                                                      const float* __restrict__ g2,
                                                      h1* __restrict__ t1,
                                                      h1* __restrict__ t2,
                                                      unsigned* __restrict__ wpk,
                                                      const float* __restrict__ w1,
                                                      const float* __restrict__ b1,
                                                      const float* __restrict__ w2,
                                                      const float* __restrict__ w3,
                                                      const float* __restrict__ b3,
                                                      const float* __restrict__ w4) {
    int idx = blockIdx.x * 256 + threadIdx.x;  // 1,048,576 total
    if (idx < 524288) {                        // grid1 [b][c][z][y][x] linear read
        int x = idx & 15, y = (idx >> 4) & 15, z = (idx >> 8) & 7;
        int c = (idx >> 11) & 31, b = idx >> 16;
        t1[((((b * 16 + y) * 16 + x) * 8 + z) << 5) + c] = (h1)g1[idx];
    } else if (idx < 966656) {                 // grid2 (8*27*2048 = 442368)
        int j = idx - 524288;
        int x = j & 15, y = (j >> 4) & 15, z = (j >> 8) & 7;
        int r = j >> 11;
        int c = r % 27, b = r / 27;
        t2[((((b * 16 + y) * 16 + x) * 8 + z) << 5) + c] = (h1)g2[j];
    } else {                                   // zero 5 pad channels
        int k = idx - 966656;
        int cell = k / 5, p = k - cell * 5;
        t2[(cell << 5) + 27 + p] = (h1)0.0f;
    }
    if (blockIdx.x == 4095) {
        int t = threadIdx.x;
        if (t < 24) {                          // w1pk
            int i = t >> 3, n = t & 7;
            wpk[t] = packh(w1[2 * n * 3 + i], w1[(2 * n + 1) * 3 + i]);
        } else if (t < 32) {
            int n = t - 24;
            wpk[t] = packh(b1[2 * n], b1[2 * n + 1]);
        } else if (t < 40) {
            int n = t - 32;
            wpk[t] = packh(w2[2 * n], w2[2 * n + 1]);
        } else if (t < 104) {
            int k = t - 40;
            int n = k >> 3, i = k & 7;
            wpk[t] = packh(w3[2 * n * 8 + i], w3[(2 * n + 1) * 8 + i]);
        } else if (t < 112) {
            int n = t - 104;
            wpk[t] = packh(w4[2 * n], w4[2 * n + 1]);
        } else if (t < 120) {
            int n = t - 112;
            wpk[t] = packh(b3[2 * n], b3[2 * n + 1]);
        }
    }
}

// ---- fused pipeline; one block = one full row (512 pixels), 2 pixels per thread
template <bool TR>
__global__ __launch_bounds__(256, 4) void fused6(
    const float* __restrict__ src,
    const void* __restrict__ g1p,
    const void* __restrict__ g2p,
    const unsigned* __restrict__ wpk,
    const float* __restrict__ w1, const float* __restrict__ b1,
    const float* __restrict__ w2, const float* __restrict__ b2,
    const float* __restrict__ w3, const float* __restrict__ b3,
    const float* __restrict__ w4, const float* __restrict__ b4,
    float* __restrict__ out) {
    __shared__ __align__(16) h1 L1h[LSLOTH];
    __shared__ __align__(16) h1 L2h[LSLOTH];

    int tid = threadIdx.x;
    int h = blockIdx.x & 511;
    int b = blockIdx.x >> 9;

    float fy = (float)h * (15.0f / 512.0f);
    int y0 = (int)fy;
    float wy = fy - (float)y0;

    const float* sbase = src + (size_t)b * 3 * HWSZ + (size_t)h * IMW;
    float sA0 = sbase[tid],       sA1 = sbase[HWSZ + tid],       sA2 = sbase[2 * HWSZ + tid];
    float sB0 = sbase[tid + 256], sB1 = sbase[HWSZ + tid + 256], sB2 = sbase[2 * HWSZ + tid + 256];

    // ---------------- stage y-interpolated fp16 slabs into LDS ----------------
    if (TR) {
        h2 wyh = (h2)(h1)wy;
        const uint4* p1 = (const uint4*)g1p + ((size_t)b * 16 + y0) * 512;
        const uint4* p2 = (const uint4*)g2p + ((size_t)b * 16 + y0) * 512;
#pragma unroll
        for (int t = tid; t < 512; t += 256) {
            int g = t & 3, cell = t >> 2;
            V16 v0, v1, r0;
            v0.u = p1[t];
            v1.u = p1[t + 512];
#pragma unroll
            for (int k = 0; k < 4; ++k) r0.h[k] = v0.h[k] + (v1.h[k] - v0.h[k]) * wyh;
            *(uint4*)&L1h[cell * CPADH + 8 * g] = r0.u;
            V16 u0, u1, r1;
            u0.u = p2[t];
            u1.u = p2[t + 512];
#pragma unroll
            for (int k = 0; k < 4; ++k) r1.h[k] = u0.h[k] + (u1.h[k] - u0.h[k]) * wyh;
            *(uint4*)&L2h[cell * CPADH + 8 * g] = r1.u;
        }
    } else {
        const float* g1f = (const float*)g1p;
        const float* g2f = (const float*)g2p;
        for (int t = tid; t < L_CELLS * CH; t += 256) {
            int c = t & 31, cell = t >> 5;
            int z = cell & 7, xj = cell >> 3;
            size_t o0 = ((((size_t)b * 32 + c) * 8 + z) * 16 + y0) * 16 + xj;
            float v0 = g1f[o0], v1 = g1f[o0 + 16];
            L1h[cell * CPADH + c] = (h1)fmaf(wy, v1 - v0, v0);
        }
        for (int t = tid; t < L_CELLS * CH; t += 256) {
            int c = t & 31, cell = t >> 5;
            int z = cell & 7, xj = cell >> 3;
            float v = 0.0f;
            if (c < 27) {
                size_t o0 = ((((size_t)b * 27 + c) * 8 + z) * 16 + y0) * 16 + xj;
                v = fmaf(wy, g2f[o0 + 16] - g2f[o0], g2f[o0]);
            }
            L2h[cell * CPADH + c] = (h1)v;
        }
    }
    __syncthreads();

    float* obase = out + (size_t)b * 3 * HWSZ + (size_t)h * IMW;
#pragma unroll 2
    for (int p = 0; p < 2; ++p) {
        int w = tid + (p << 8);
        float s0 = p ? sB0 : sA0;
        float s1 = p ? sB1 : sA1;
        float s2 = p ? sB2 : sA2;

        // ---- guide MLP #1: 3 -> 16 -> 1 ----
        float acc;
        h2 s0h, s1h, s2h;
        if constexpr (TR) {
            s0h = (h2)(h1)s0;
            s1h = (h2)(h1)s1;
            s2h = (h2)(h1)s2;
            h2 A;
#pragma unroll
            for (int n = 0; n < 8; ++n) {
                h2 t = ash2(wpk[24 + n]);
                t += s0h * ash2(wpk[n]);
                t += s1h * ash2(wpk[8 + n]);
                t += s2h * ash2(wpk[16 + n]);
                t = pkmax0(t);
                if (n == 0) A = t * ash2(wpk[32]);
                else        A += t * ash2(wpk[32 + n]);
            }
            acc = b2[0] + (float)A[0] + (float)A[1];
        } else {
            acc = b2[0];
#pragma unroll
            for (int j = 0; j < 16; ++j) {
                float t = fmaf(w1[j * 3 + 0], s0,
                          fmaf(w1[j * 3 + 1], s1,
                          fmaf(w1[j * 3 + 2], s2, b1[j])));
                acc = fmaf(w2[j], fmaxf(t, 0.0f), acc);
            }
        }
        float fz = fmaf(fast_tanh(acc), 3.5f, 3.5f);
        fz = fminf(fmaxf(fz, 0.0f), 7.0f);
        int z0 = min((int)fz, 6);
        float wz = fz - (float)z0;

        float fx = (float)w * (15.0f / 512.0f);
        int x0 = (int)fx;
        float wx = fx - (float)x0;
        int a00 = (x0 * 8 + z0) * CPADH;

        float w11v = wx * wz;
        float w10v = wx - w11v;
        float w01v = wz - w11v;
        float w00v = 1.0f - wx - wz + w11v;
        h2 W00 = (h2)(h1)w00v, W01 = (h2)(h1)w01v, W10 = (h2)(h1)w10v, W11 = (h2)(h1)w11v;

        // ---- slice 1: bilinear (x,z) over 32 ch, packed fp16, result stays h2 ----
        const uint4* p00 = (const uint4*)&L1h[a00];
        const uint4* p01 = (const uint4*)&L1h[a00 + CPADH];
        const uint4* p10 = (const uint4*)&L1h[a00 + 8 * CPADH];
        const uint4* p11 = (const uint4*)&L1h[a00 + 9 * CPADH];
        h2 c1h[16];   // pair m holds channels (2m, 2m+1); channel c = i*8+o
#pragma unroll
        for (int j = 0; j < 4; ++j) {
            V16 A, B, C, D;
            A.u = p00[j];
            B.u = p01[j];
            C.u = p10[j];
            D.u = p11[j];
#pragma unroll
            for (int k = 0; k < 4; ++k)
                c1h[j * 4 + k] = A.h[k] * W00 + B.h[k] * W01 + C.h[k] * W10 + D.h[k] * W11;
        }

        // ---- affine #1: hidden = relu(coeff1 * src) ----
        h2 hidh[4];
        float hidf[8];
        if constexpr (TR) {
#pragma unroll
            for (int n = 0; n < 4; ++n) {
                h2 t = c1h[12 + n];
                t += c1h[n] * s0h;
                t += c1h[4 + n] * s1h;
                t += c1h[8 + n] * s2h;
                hidh[n] = pkmax0(t);
                hidf[2 * n]     = (float)hidh[n][0];
                hidf[2 * n + 1] = (float)hidh[n][1];
            }
        } else {
#pragma unroll
            for (int o = 0; o < 8; ++o) {
                float t = fmaf((float)c1h[o >> 1][o & 1], s0,
                          fmaf((float)c1h[(8 + o) >> 1][o & 1], s1,
                          fmaf((float)c1h[(16 + o) >> 1][o & 1], s2,
                               (float)c1h[(24 + o) >> 1][o & 1])));
                hidf[o] = fmaxf(t, 0.0f);
            }
        }

        // ---- guide MLP #2: 8 -> 16 -> 1 ----
        float acc2;
        if constexpr (TR) {
            h2 hs[8];
#pragma unroll
            for (int n = 0; n < 4; ++n) {
                hs[2 * n]     = (h2)hidh[n][0];
                hs[2 * n + 1] = (h2)hidh[n][1];
            }
            h2 A;
#pragma unroll
            for (int n = 0; n < 8; ++n) {
                h2 t = ash2(wpk[112 + n]);
#pragma unroll
                for (int i = 0; i < 8; ++i) t += hs[i] * ash2(wpk[40 + n * 8 + i]);
                t = pkmax0(t);
                if (n == 0) A = t * ash2(wpk[104]);
                else        A += t * ash2(wpk[104 + n]);
            }
            acc2 = b4[0] + (float)A[0] + (float)A[1];
        } else {
            acc2 = b4[0];
#pragma unroll
            for (int j = 0; j < 16; ++j) {
                float t = b3[j];
#pragma unroll
                for (int i = 0; i < 8; ++i) t = fmaf(w3[j * 8 + i], hidf[i], t);
                acc2 = fmaf(w4[j], fmaxf(t, 0.0f), acc2);
            }
        }
        float fz2 = fmaf(fast_tanh(acc2), 3.5f, 3.5f);
        fz2 = fminf(fmaxf(fz2, 0.0f), 7.0f);
        int z0b = min((int)fz2, 6);
        float wz2 = fz2 - (float)z0b;

        int a00b = (x0 * 8 + z0b) * CPADH;
        float u11 = wx * wz2;
        float u10 = wx - u11;
        float u01 = wz2 - u11;
        float u00 = 1.0f - wx - wz2 + u11;
        h2 U00 = (h2)(h1)u00, U01 = (h2)(h1)u01, U10 = (h2)(h1)u10, U11 = (h2)(h1)u11;

        // ---- slice 2: bilinear (x,z) over 27 ch (+pad), packed fp16 ----
        const uint4* q00 = (const uint4*)&L2h[a00b];
        const uint4* q01 = (const uint4*)&L2h[a00b + CPADH];
        const uint4* q10 = (const uint4*)&L2h[a00b + 8 * CPADH];
        const uint4* q11 = (const uint4*)&L2h[a00b + 9 * CPADH];
        h2 c2h[14];
#pragma unroll
        for (int j = 0; j < 4; ++j) {
            V16 A, B, C, D;
            A.u = q00[j];
            B.u = q01[j];
            C.u = q10[j];
            D.u = q11[j];
#pragma unroll
            for (int k = 0; k < 4; ++k) {
                int m = j * 4 + k;
                if (m < 14)
                    c2h[m] = A.h[k] * U00 + B.h[k] * U01 + C.h[k] * U10 + D.h[k] * U11;
            }
        }

        // ---- affine #2 (fp32, inline cvts) ----
#pragma unroll
        for (int o = 0; o < 3; ++o) {
            float t = (float)c2h[(24 + o) >> 1][(24 + o) & 1];
#pragma unroll
            for (int i = 0; i < 8; ++i) {
                int c = i * 3 + o;
                t = fmaf((float)c2h[c >> 1][c & 1], hidf[i], t);
            }
            obase[(size_t)o * HWSZ + w] = t;
        }
    }
}

extern "C" void kernel_launch(void* const* d_in, const int* in_sizes, int n_in,
                              void* d_out, int out_size, void* d_ws, size_t ws_size,
                              hipStream_t stream) {
    const float* src   = (const float*)d_in[0];
    const float* grid1 = (const float*)d_in[1];
    const float* grid2 = (const float*)d_in[2];
    const float* w1 = (const float*)d_in[3];
    const float* b1 = (const float*)d_in[4];
    const float* w2 = (const float*)d_in[5];
    const float* b2 = (const float*)d_in[6];
    const float* w3 = (const float*)d_in[7];
    const float* b3 = (const float*)d_in[8];
    const float* w4 = (const float*)d_in[9];
    const float* b4 = (const float*)d_in[10];
    float* out = (float*)d_out;

    const size_t t_elems = (size_t)BATCH * 2048 * CH;     // 524288 halves each
    const size_t ws_needed = 2 * t_elems * sizeof(h1) + 512;

    const int nblk = BATCH * IMH;                         // 4096 (one row each)

    if (ws_size >= ws_needed) {
        h1* t1 = (h1*)d_ws;
        h1* t2 = t1 + t_elems;
        unsigned* wpk = (unsigned*)(t2 + t_elems);
        transpose_both<<<4096, 256, 0, stream>>>(grid1, grid2, t1, t2, wpk,
                                                 w1, b1, w2, w3, b3, w4);
        fused6<true><<<nblk, 256, 0, stream>>>(
            src, t1, t2, wpk, w1, b1, w2, b2, w3, b3, w4, b4, out);
    } else {
        fused6<false><<<nblk, 256, 0, stream>>>(
            src, grid1, grid2, nullptr, w1, b1, w2, b2, w3, b3, w4, b4, out);
    }
}